// Round 4
// baseline (432.972 us; speedup 1.0000x reference)
//
#include <hip/hip_runtime.h>
#include <hip/hip_bf16.h>

// B=2, S=2048, D=1024, H=16, DH=64, BLK=128, NB=16
// Inputs are FLOAT32 (per harness contract); converted on-device to bf16 for MFMA.
// Output is FLOAT32. Mask dtype sniffed at runtime (f32/bf16/f16/u8/i32/i64).

typedef __attribute__((ext_vector_type(4))) float f32x4;
typedef __attribute__((ext_vector_type(8))) short bf16x8;

#define MFMA16(a, b, c) __builtin_amdgcn_mfma_f32_16x16x32_bf16(a, b, c, 0, 0, 0)
#define LOG2E 1.4426950408889634f

// ---------------- f32 -> bf16 (RNE) conversion, 8 elems/thread ----------------
__device__ inline unsigned short f2bf(float f) {
  unsigned u = __builtin_bit_cast(unsigned, f);
  unsigned rounding = 0x7FFFu + ((u >> 16) & 1u);
  return (unsigned short)((u + rounding) >> 16);
}

__global__ __launch_bounds__(256) void cvt_kernel(const float* __restrict__ in,
                                                  unsigned short* __restrict__ out, int n8) {
  const int i = blockIdx.x * 256 + threadIdx.x;
  if (i >= n8) return;
  const float4* p = (const float4*)in + (size_t)i * 2;
  const float4 a = p[0], b = p[1];
  union { unsigned short u[8]; uint4 v; } r;
  r.u[0] = f2bf(a.x); r.u[1] = f2bf(a.y); r.u[2] = f2bf(a.z); r.u[3] = f2bf(a.w);
  r.u[4] = f2bf(b.x); r.u[5] = f2bf(b.y); r.u[6] = f2bf(b.z); r.u[7] = f2bf(b.w);
  *((uint4*)out + i) = r.v;
}

// ---------------- robust mask reader: sniff dtype from first 256 bytes ----------------
__device__ inline int mask_mode(const void* maskp) {
  const unsigned short* mh = (const unsigned short*)maskp;
  const unsigned* mw = (const unsigned*)maskp;
  bool anyFloatHalf = false;
  for (int t = 0; t < 128; ++t) {
    const unsigned short v = mh[t];
    if (v == 0x3F80u || v == 0x3C00u) { anyFloatHalf = true; break; }
  }
  if (anyFloatHalf) {
    bool evenNZ = false;
    for (int t = 0; t < 128; t += 2)
      if (mh[t] != 0) { evenNZ = true; break; }
    return evenNZ ? 1 : 0;  // 1 = bf16/f16, 0 = f32
  }
  bool anyBig = false;
  for (int t = 0; t < 64; ++t)
    if (mw[t] > 1u) { anyBig = true; break; }
  if (anyBig) return 2;  // packed u8
  bool oddNZ = false;
  for (int t = 1; t < 64; t += 2)
    if (mw[t] != 0u) { oddNZ = true; break; }
  return oddNZ ? 3 : 4;  // 3 = i32, 4 = i64
}

__device__ inline int mask_read(const void* maskp, int mode, int idx) {
  switch (mode) {
    case 0: return ((const unsigned*)maskp)[idx] != 0u;
    case 1: return ((const unsigned short*)maskp)[idx] != 0;
    case 2: return ((const unsigned char*)maskp)[idx] != 0;
    case 3: return ((const int*)maskp)[idx] != 0;
    default: return ((const unsigned*)maskp)[idx * 2] != 0u ||
                    ((const unsigned*)maskp)[idx * 2 + 1] != 0u;
  }
}

// ---------------- staging: 128x32 bf16 tile, global -> LDS (linear), width 16 ----------------
__device__ inline void stage_tile_128x32(const __hip_bfloat16* g, int ld_elems,
                                         __hip_bfloat16* lds, int wave, int lane) {
#pragma unroll
  for (int i = 0; i < 2; ++i) {
    const int chunk = wave * 2 + i;
    const int o = chunk * 1024 + lane * 16;
    const int r = o >> 6;
    const int cb = o & 63;
    const char* ga = (const char*)g + (size_t)r * ld_elems * 2 + cb;
    __builtin_amdgcn_global_load_lds(
        (const __attribute__((address_space(1))) unsigned int*)ga,
        (__attribute__((address_space(3))) unsigned int*)((char*)lds + chunk * 1024),
        16, 0, 0);
  }
}

// ---------------- GEMM: C = A @ W^T. MODE 0: fused QKV -> bf16. MODE 1: +f32 bias -> f32 out.
template <int MODE>
__global__ __launch_bounds__(256) void gemm_bt(
    const __hip_bfloat16* __restrict__ A,
    const __hip_bfloat16* __restrict__ W0, const __hip_bfloat16* __restrict__ W1,
    const __hip_bfloat16* __restrict__ W2,
    const float* __restrict__ bias,
    __hip_bfloat16* __restrict__ OutB, float* __restrict__ OutF, int K) {
  __shared__ __hip_bfloat16 sA[128 * 32];
  __shared__ __hip_bfloat16 sB[128 * 32];
  const int tid = threadIdx.x;
  const int wave = tid >> 6, lane = tid & 63;
  const int lr = lane & 15, lg = lane >> 4;
  const int wr = wave >> 1, wc = wave & 1;
  const int m0 = blockIdx.x * 128;

  const __hip_bfloat16* W;
  __hip_bfloat16* OB = nullptr;
  int n0;
  if (MODE == 0) {
    const int sel = blockIdx.y >> 3;
    n0 = (blockIdx.y & 7) * 128;
    W = (sel == 0) ? W0 : ((sel == 1) ? W1 : W2);
    OB = OutB + (size_t)sel * 4194304ull;
  } else {
    n0 = blockIdx.y * 128;
    W = W0;
  }

  f32x4 acc[4][4] = {};
  for (int k0 = 0; k0 < K; k0 += 32) {
    stage_tile_128x32(A + (size_t)m0 * K + k0, K, sA, wave, lane);
    stage_tile_128x32(W + (size_t)n0 * K + k0, K, sB, wave, lane);
    __syncthreads();

    bf16x8 af[4], bfr[4];
#pragma unroll
    for (int mi = 0; mi < 4; ++mi)
      af[mi] = *(const bf16x8*)(sA + (64 * wr + 16 * mi + lr) * 32 + lg * 8);
#pragma unroll
    for (int ni = 0; ni < 4; ++ni)
      bfr[ni] = *(const bf16x8*)(sB + (64 * wc + 16 * ni + lr) * 32 + lg * 8);
#pragma unroll
    for (int mi = 0; mi < 4; ++mi)
#pragma unroll
      for (int ni = 0; ni < 4; ++ni)
        acc[mi][ni] = MFMA16(af[mi], bfr[ni], acc[mi][ni]);
    __syncthreads();
  }

#pragma unroll
  for (int mi = 0; mi < 4; ++mi)
#pragma unroll
    for (int ni = 0; ni < 4; ++ni)
#pragma unroll
      for (int q = 0; q < 4; ++q) {
        const int m = m0 + 64 * wr + 16 * mi + lg * 4 + q;
        const int n = n0 + 64 * wc + 16 * ni + lr;
        if (MODE == 0) {
          OB[(size_t)m * 1024 + n] = __float2bfloat16(acc[mi][ni][q]);
        } else {
          OutF[(size_t)m * 1024 + n] = acc[mi][ni][q] + bias[n];
        }
      }
}

// ---------------- block-sparse flash attention (bf16 in, bf16 out) ----------------
// grid: (16 q-blocks, 32 b*h). block: 256 threads = 4 waves, wave owns 32 q rows.
__global__ __launch_bounds__(256) void attn_kernel(
    const __hip_bfloat16* __restrict__ Q, const __hip_bfloat16* __restrict__ K,
    const __hip_bfloat16* __restrict__ V, const void* __restrict__ maskp,
    __hip_bfloat16* __restrict__ O) {
  __shared__ __hip_bfloat16 P_lds[4][32][136];  // +8 pad kills bank conflicts
  const int qb = blockIdx.x;
  const int bh = blockIdx.y;
  const int b = bh >> 4, h = bh & 15;
  const int tid = threadIdx.x, wave = tid >> 6, lane = tid & 63;
  const int lr = lane & 15, lg = lane >> 4;

  const int mmode = mask_mode(maskp);
  int keep[16], nkeep = 0;
  for (int j = 0; j < 16; ++j)
    if (mask_read(maskp, mmode, qb * 16 + j)) keep[nkeep++] = j;

  const size_t base = (size_t)b * 2048 * 1024 + h * 64;  // [B,S,H*DH]
  const int qrow0 = qb * 128 + wave * 32;

  bf16x8 qf[2][2];
#pragma unroll
  for (int mt = 0; mt < 2; ++mt)
#pragma unroll
    for (int ks = 0; ks < 2; ++ks)
      qf[mt][ks] = *(const bf16x8*)(Q + base + (size_t)(qrow0 + 16 * mt + lr) * 1024 + ks * 32 + lg * 8);

  f32x4 oa[2][4] = {};
  float mrun[2][4], lrun[2][4];
#pragma unroll
  for (int mt = 0; mt < 2; ++mt)
#pragma unroll
    for (int q = 0; q < 4; ++q) { mrun[mt][q] = -1e30f; lrun[mt][q] = 0.f; }

  for (int ji = 0; ji < nkeep; ++ji) {
    const int j = keep[ji];
    const size_t kbase = base + (size_t)j * 128 * 1024;

    // ---- S = Q K^T ----
    f32x4 s[2][8] = {};
#pragma unroll
    for (int ks = 0; ks < 2; ++ks) {
#pragma unroll
      for (int nt = 0; nt < 8; ++nt) {
        bf16x8 kf = *(const bf16x8*)(K + kbase + (size_t)(16 * nt + lr) * 1024 + ks * 32 + lg * 8);
        s[0][nt] = MFMA16(qf[0][ks], kf, s[0][nt]);
        s[1][nt] = MFMA16(qf[1][ks], kf, s[1][nt]);
      }
    }

    // ---- online softmax (16-lane-group reduce; C/D col=lane&15, row=lg*4+q) ----
#pragma unroll
    for (int mt = 0; mt < 2; ++mt) {
#pragma unroll
      for (int q = 0; q < 4; ++q) {
        float rm = -1e30f;
#pragma unroll
        for (int nt = 0; nt < 8; ++nt) {
          s[mt][nt][q] *= 0.125f;
          rm = fmaxf(rm, s[mt][nt][q]);
        }
        rm = fmaxf(rm, __shfl_xor(rm, 1));
        rm = fmaxf(rm, __shfl_xor(rm, 2));
        rm = fmaxf(rm, __shfl_xor(rm, 4));
        rm = fmaxf(rm, __shfl_xor(rm, 8));
        const float mold = mrun[mt][q];
        const float mnew = fmaxf(mold, rm);
        const float sf = exp2f((mold - mnew) * LOG2E);
        float rs = 0.f;
#pragma unroll
        for (int nt = 0; nt < 8; ++nt) {
          const float p = exp2f((s[mt][nt][q] - mnew) * LOG2E);
          s[mt][nt][q] = p;
          rs += p;
        }
        rs += __shfl_xor(rs, 1);
        rs += __shfl_xor(rs, 2);
        rs += __shfl_xor(rs, 4);
        rs += __shfl_xor(rs, 8);
        lrun[mt][q] = lrun[mt][q] * sf + rs;
        mrun[mt][q] = mnew;
#pragma unroll
        for (int ni = 0; ni < 4; ++ni) oa[mt][ni][q] *= sf;
      }
    }

    // ---- P -> LDS (bf16) ----
#pragma unroll
    for (int mt = 0; mt < 2; ++mt)
#pragma unroll
      for (int nt = 0; nt < 8; ++nt)
#pragma unroll
        for (int q = 0; q < 4; ++q)
          P_lds[wave][16 * mt + lg * 4 + q][16 * nt + lr] = __float2bfloat16(s[mt][nt][q]);
    __syncthreads();

    // ---- O += P V ----
#pragma unroll
    for (int ks = 0; ks < 4; ++ks) {
      bf16x8 pa0 = *(const bf16x8*)&P_lds[wave][lr][ks * 32 + lg * 8];
      bf16x8 pa1 = *(const bf16x8*)&P_lds[wave][16 + lr][ks * 32 + lg * 8];
#pragma unroll
      for (int ni = 0; ni < 4; ++ni) {
        bf16x8 vb;
        const short* Vs = (const short*)V;
#pragma unroll
        for (int jj = 0; jj < 8; ++jj)
          vb[jj] = Vs[kbase + (size_t)(ks * 32 + lg * 8 + jj) * 1024 + 16 * ni + lr];
        oa[0][ni] = MFMA16(pa0, vb, oa[0][ni]);
        oa[1][ni] = MFMA16(pa1, vb, oa[1][ni]);
      }
    }
    __syncthreads();
  }

  // ---- epilogue: O / l (clamped denominator) ----
#pragma unroll
  for (int mt = 0; mt < 2; ++mt)
#pragma unroll
    for (int ni = 0; ni < 4; ++ni)
#pragma unroll
      for (int q = 0; q < 4; ++q) {
        const int row = qrow0 + 16 * mt + lg * 4 + q;
        const float v = oa[mt][ni][q] / fmaxf(lrun[mt][q], 1e-30f);
        O[base + (size_t)row * 1024 + 16 * ni + lr] = __float2bfloat16(v);
      }
}

extern "C" void kernel_launch(void* const* d_in, const int* in_sizes, int n_in,
                              void* d_out, int out_size, void* d_ws, size_t ws_size,
                              hipStream_t stream) {
  const float* x  = (const float*)d_in[0];
  const float* Wq = (const float*)d_in[1];
  const float* Wk = (const float*)d_in[2];
  const float* Wv = (const float*)d_in[3];
  const float* Wo = (const float*)d_in[4];
  const float* bo = (const float*)d_in[5];
  const void* mask = d_in[6];
  float* out = (float*)d_out;

  // ws layout (bf16 elements)
  __hip_bfloat16* ws = (__hip_bfloat16*)d_ws;
  __hip_bfloat16* xb  = ws;                         // 4096x1024
  __hip_bfloat16* Wqb = ws + 4194304ull;            // 1024x1024
  __hip_bfloat16* Wkb = ws + 5242880ull;
  __hip_bfloat16* Wvb = ws + 6291456ull;
  __hip_bfloat16* Wob = ws + 7340032ull;
  __hip_bfloat16* Qb  = ws + 8388608ull;            // Q,K,V: 4096x1024 each
  __hip_bfloat16* Ob  = ws + 20971520ull;           // 4096x1024

  dim3 blk(256);
  // f32 -> bf16 conversions
  cvt_kernel<<<2048, blk, 0, stream>>>(x,  (unsigned short*)xb,  524288);
  cvt_kernel<<<512,  blk, 0, stream>>>(Wq, (unsigned short*)Wqb, 131072);
  cvt_kernel<<<512,  blk, 0, stream>>>(Wk, (unsigned short*)Wkb, 131072);
  cvt_kernel<<<512,  blk, 0, stream>>>(Wv, (unsigned short*)Wvb, 131072);
  cvt_kernel<<<512,  blk, 0, stream>>>(Wo, (unsigned short*)Wob, 131072);
  // QKV fused projection: grid (4096/128, 3*1024/128)
  gemm_bt<0><<<dim3(32, 24), blk, 0, stream>>>(xb, Wqb, Wkb, Wvb, nullptr, Qb, nullptr, 1024);
  // block-sparse flash attention
  attn_kernel<<<dim3(16, 32), blk, 0, stream>>>(Qb, Qb + 4194304ull, Qb + 2ull * 4194304ull,
                                                mask, Ob);
  // output projection + bias -> f32 d_out
  gemm_bt<1><<<dim3(32, 8), blk, 0, stream>>>(Ob, Wob, nullptr, nullptr, bo, nullptr, out, 1024);
}

// Round 8
// 341.249 us; speedup vs baseline: 1.2688x; 1.2688x over previous
//
#include <hip/hip_runtime.h>
#include <hip/hip_bf16.h>

// B=2, S=2048, D=1024, H=16, DH=64, BLK=128, NB=16
// Inputs FLOAT32 -> converted on-device to bf16. Output FLOAT32.
// V-projection GEMM writes V^T (Vt[b][d][s]) by swapping MFMA operands.
// Attention: LDS-staged K/Vt tiles, XOR-swizzled (conflict-free ds_read_b128).

typedef __attribute__((ext_vector_type(4))) float f32x4;
typedef __attribute__((ext_vector_type(8))) short bf16x8;

#define MFMA16(a, b, c) __builtin_amdgcn_mfma_f32_16x16x32_bf16(a, b, c, 0, 0, 0)
#define LOG2E 1.4426950408889634f

// ---------------- f32 -> bf16 (RNE), 8 elems/thread ----------------
__device__ inline unsigned short f2bf(float f) {
  unsigned u = __builtin_bit_cast(unsigned, f);
  unsigned rounding = 0x7FFFu + ((u >> 16) & 1u);
  return (unsigned short)((u + rounding) >> 16);
}

__global__ __launch_bounds__(256) void cvt_kernel(const float* __restrict__ in,
                                                  unsigned short* __restrict__ out, int n8) {
  const int i = blockIdx.x * 256 + threadIdx.x;
  if (i >= n8) return;
  const float4* p = (const float4*)in + (size_t)i * 2;
  const float4 a = p[0], b = p[1];
  union { unsigned short u[8]; uint4 v; } r;
  r.u[0] = f2bf(a.x); r.u[1] = f2bf(a.y); r.u[2] = f2bf(a.z); r.u[3] = f2bf(a.w);
  r.u[4] = f2bf(b.x); r.u[5] = f2bf(b.y); r.u[6] = f2bf(b.z); r.u[7] = f2bf(b.w);
  *((uint4*)out + i) = r.v;
}

// ---------------- mask dtype sniffer ----------------
__device__ inline int mask_mode(const void* maskp) {
  const unsigned short* mh = (const unsigned short*)maskp;
  const unsigned* mw = (const unsigned*)maskp;
  bool anyFloatHalf = false;
  for (int t = 0; t < 128; ++t) {
    const unsigned short v = mh[t];
    if (v == 0x3F80u || v == 0x3C00u) { anyFloatHalf = true; break; }
  }
  if (anyFloatHalf) {
    bool evenNZ = false;
    for (int t = 0; t < 128; t += 2)
      if (mh[t] != 0) { evenNZ = true; break; }
    return evenNZ ? 1 : 0;  // 1 = bf16/f16, 0 = f32
  }
  bool anyBig = false;
  for (int t = 0; t < 64; ++t)
    if (mw[t] > 1u) { anyBig = true; break; }
  if (anyBig) return 2;  // packed u8
  bool oddNZ = false;
  for (int t = 1; t < 64; t += 2)
    if (mw[t] != 0u) { oddNZ = true; break; }
  return oddNZ ? 3 : 4;  // 3 = i32, 4 = i64
}

__device__ inline int mask_read(const void* maskp, int mode, int idx) {
  switch (mode) {
    case 0: return ((const unsigned*)maskp)[idx] != 0u;
    case 1: return ((const unsigned short*)maskp)[idx] != 0;
    case 2: return ((const unsigned char*)maskp)[idx] != 0;
    case 3: return ((const int*)maskp)[idx] != 0;
    default: return ((const unsigned*)maskp)[idx * 2] != 0u ||
                    ((const unsigned*)maskp)[idx * 2 + 1] != 0u;
  }
}

// ---------------- GEMM staging: 128x32 bf16 tile, linear ----------------
__device__ inline void stage_tile_128x32(const __hip_bfloat16* g, int ld_elems,
                                         __hip_bfloat16* lds, int wave, int lane) {
#pragma unroll
  for (int i = 0; i < 2; ++i) {
    const int chunk = wave * 2 + i;
    const int o = chunk * 1024 + lane * 16;
    const int r = o >> 6;
    const int cb = o & 63;
    const char* ga = (const char*)g + (size_t)r * ld_elems * 2 + cb;
    __builtin_amdgcn_global_load_lds(
        (const __attribute__((address_space(1))) unsigned int*)ga,
        (__attribute__((address_space(3))) unsigned int*)((char*)lds + chunk * 1024),
        16, 0, 0);
  }
}

// ---------------- GEMM: C = A @ W^T.
// MODE 0: fused Q,K (sel=blockIdx.y>>3) -> bf16 [4096][1024] each.
// MODE 1: out proj + f32 bias -> f32 d_out.
// MODE 2: V^T via swapped MFMA operands -> Vt[b][1024][2048] bf16.
template <int MODE>
__global__ __launch_bounds__(256) void gemm_bt(
    const __hip_bfloat16* __restrict__ A,
    const __hip_bfloat16* __restrict__ W0, const __hip_bfloat16* __restrict__ W1,
    const float* __restrict__ bias,
    __hip_bfloat16* __restrict__ OutB, float* __restrict__ OutF, int K) {
  __shared__ __hip_bfloat16 sA[128 * 32];
  __shared__ __hip_bfloat16 sB[128 * 32];
  const int tid = threadIdx.x;
  const int wave = tid >> 6, lane = tid & 63;
  const int lr = lane & 15, lg = lane >> 4;
  const int wr = wave >> 1, wc = wave & 1;
  const int m0 = blockIdx.x * 128;

  const __hip_bfloat16* W;
  __hip_bfloat16* OB = nullptr;
  int n0;
  if (MODE == 0) {
    const int sel = blockIdx.y >> 3;
    n0 = (blockIdx.y & 7) * 128;
    W = sel ? W1 : W0;
    OB = OutB + (size_t)sel * 4194304ull;
  } else {
    n0 = blockIdx.y * 128;
    W = W0;
    OB = OutB;
  }

  f32x4 acc[4][4] = {};
  for (int k0 = 0; k0 < K; k0 += 32) {
    stage_tile_128x32(A + (size_t)m0 * K + k0, K, sA, wave, lane);
    stage_tile_128x32(W + (size_t)n0 * K + k0, K, sB, wave, lane);
    __syncthreads();

    bf16x8 af[4], bfr[4];
#pragma unroll
    for (int mi = 0; mi < 4; ++mi)
      af[mi] = *(const bf16x8*)(sA + (64 * wr + 16 * mi + lr) * 32 + lg * 8);
#pragma unroll
    for (int ni = 0; ni < 4; ++ni)
      bfr[ni] = *(const bf16x8*)(sB + (64 * wc + 16 * ni + lr) * 32 + lg * 8);
#pragma unroll
    for (int i = 0; i < 4; ++i)
#pragma unroll
      for (int jj = 0; jj < 4; ++jj)
        acc[i][jj] = (MODE == 2) ? MFMA16(bfr[i], af[jj], acc[i][jj])   // C^T = W . x^T
                                 : MFMA16(af[i], bfr[jj], acc[i][jj]);
    __syncthreads();
  }

  if (MODE == 2) {
    // acc[i][jj]: row-dim = n (weight row), col-dim = m (token).
#pragma unroll
    for (int i = 0; i < 4; ++i)
#pragma unroll
      for (int jj = 0; jj < 4; ++jj)
#pragma unroll
        for (int q = 0; q < 4; ++q) {
          const int n = n0 + 64 * wc + 16 * i + lg * 4 + q;
          const int m = m0 + 64 * wr + 16 * jj + lr;
          OB[((size_t)(m >> 11) * 1024 + n) * 2048 + (m & 2047)] =
              __float2bfloat16(acc[i][jj][q]);
        }
  } else {
#pragma unroll
    for (int i = 0; i < 4; ++i)
#pragma unroll
      for (int jj = 0; jj < 4; ++jj)
#pragma unroll
        for (int q = 0; q < 4; ++q) {
          const int m = m0 + 64 * wr + 16 * i + lg * 4 + q;
          const int n = n0 + 64 * wc + 16 * jj + lr;
          if (MODE == 0) OB[(size_t)m * 1024 + n] = __float2bfloat16(acc[i][jj][q]);
          else           OutF[(size_t)m * 1024 + n] = acc[i][jj][q] + bias[n];
        }
  }
}

// ---------------- block-sparse flash attention ----------------
// grid: (16 q-blocks, 32 b*h). 4 waves, wave owns 32 q rows.
// LDS: union{ K-tile 16KB | P 34.8KB } + Vt-tile 16KB = 50KB.
__global__ __launch_bounds__(256) void attn_kernel(
    const __hip_bfloat16* __restrict__ Q, const __hip_bfloat16* __restrict__ K,
    const __hip_bfloat16* __restrict__ Vt, const void* __restrict__ maskp,
    __hip_bfloat16* __restrict__ O) {
  __shared__ char uKP[4 * 32 * 136 * 2];   // K tile [128][64] swz  |  P [4][32][136]
  __shared__ char sV[64 * 256];            // Vt tile [64 d][128 s] swz
  __hip_bfloat16 (*P_lds)[32][136] = (__hip_bfloat16(*)[32][136])uKP;

  const int qb = blockIdx.x, bh = blockIdx.y;
  const int b = bh >> 4, h = bh & 15;
  const int tid = threadIdx.x, wave = tid >> 6, lane = tid & 63;
  const int lr = lane & 15, lg = lane >> 4;

  const int mmode = mask_mode(maskp);
  int keep[16], nkeep = 0;
  for (int j = 0; j < 16; ++j)
    if (mask_read(maskp, mmode, qb * 16 + j)) keep[nkeep++] = j;

  const size_t base = (size_t)b * 2048 * 1024 + (size_t)h * 64;          // Q/K/O elem base
  const char* Kbase  = (const char*)(K + base);                          // row stride 2048B
  const char* Vtbase = (const char*)Vt +
      ((size_t)b * 1024 * 2048 + (size_t)h * 64 * 2048) * 2;             // row stride 4096B
  const int qrow0 = qb * 128 + wave * 32;

  bf16x8 qf[2][2];
#pragma unroll
  for (int mt = 0; mt < 2; ++mt)
#pragma unroll
    for (int ks = 0; ks < 2; ++ks)
      qf[mt][ks] = *(const bf16x8*)(Q + base + (size_t)(qrow0 + 16 * mt + lr) * 1024 + ks * 32 + lg * 8);

  f32x4 oa[2][4] = {};
  float mrun[2][4], lrun[2][4];
#pragma unroll
  for (int mt = 0; mt < 2; ++mt)
#pragma unroll
    for (int q = 0; q < 4; ++q) { mrun[mt][q] = -1e30f; lrun[mt][q] = 0.f; }

  for (int ji = 0; ji < nkeep; ++ji) {
    const int j = keep[ji];
    const char* gK = Kbase + (size_t)j * 128 * 2048;   // K rows s=j*128.., 128B used/row
    const char* gV = Vtbase + (size_t)j * 128 * 2;     // Vt cols s=j*128.., 256B used/row

    // ---- stage K and Vt tiles (inverse-swizzled global source, linear LDS dest) ----
#pragma unroll
    for (int i = 0; i < 4; ++i) {
      const int o = (wave * 4 + i) * 1024 + lane * 16;
      { const int r = o >> 7, cb = o & 127, cbs = cb ^ ((r & 7) << 4);
        __builtin_amdgcn_global_load_lds(
            (const __attribute__((address_space(1))) unsigned*)(gK + (size_t)r * 2048 + cbs),
            (__attribute__((address_space(3))) unsigned*)(uKP + o), 16, 0, 0); }
      { const int r = o >> 8, cb = o & 255, cbs = cb ^ ((r & 7) << 4);
        __builtin_amdgcn_global_load_lds(
            (const __attribute__((address_space(1))) unsigned*)(gV + (size_t)r * 4096 + cbs),
            (__attribute__((address_space(3))) unsigned*)(sV + o), 16, 0, 0); }
    }
    __syncthreads();  // vmcnt(0) drain: K/V tiles resident

    // ---- S = Q K^T (kf: swizzled ds_read_b128, conflict-free) ----
    f32x4 s[2][8] = {};
    __builtin_amdgcn_s_setprio(1);
#pragma unroll
    for (int ks = 0; ks < 2; ++ks)
#pragma unroll
      for (int nt = 0; nt < 8; ++nt) {
        const int row = 16 * nt + lr;
        bf16x8 kf = *(const bf16x8*)(uKP + row * 128 + ((ks * 64 + lg * 16) ^ ((lr & 7) << 4)));
        s[0][nt] = MFMA16(qf[0][ks], kf, s[0][nt]);
        s[1][nt] = MFMA16(qf[1][ks], kf, s[1][nt]);
      }
    __builtin_amdgcn_s_setprio(0);

    // ---- online softmax (16-lane-group reduce) ----
#pragma unroll
    for (int mt = 0; mt < 2; ++mt) {
#pragma unroll
      for (int q = 0; q < 4; ++q) {
        float rm = -1e30f;
#pragma unroll
        for (int nt = 0; nt < 8; ++nt) {
          s[mt][nt][q] *= 0.125f;
          rm = fmaxf(rm, s[mt][nt][q]);
        }
        rm = fmaxf(rm, __shfl_xor(rm, 1));
        rm = fmaxf(rm, __shfl_xor(rm, 2));
        rm = fmaxf(rm, __shfl_xor(rm, 4));
        rm = fmaxf(rm, __shfl_xor(rm, 8));
        const float mold = mrun[mt][q];
        const float mnew = fmaxf(mold, rm);
        const float sf = exp2f((mold - mnew) * LOG2E);
        float rs = 0.f;
#pragma unroll
        for (int nt = 0; nt < 8; ++nt) {
          const float p = exp2f((s[mt][nt][q] - mnew) * LOG2E);
          s[mt][nt][q] = p;
          rs += p;
        }
        rs += __shfl_xor(rs, 1);
        rs += __shfl_xor(rs, 2);
        rs += __shfl_xor(rs, 4);
        rs += __shfl_xor(rs, 8);
        lrun[mt][q] = lrun[mt][q] * sf + rs;
        mrun[mt][q] = mnew;
#pragma unroll
        for (int ni = 0; ni < 4; ++ni) oa[mt][ni][q] *= sf;
      }
    }

    __syncthreads();  // all waves done reading K tile before P overwrites the union

    // ---- P -> LDS (bf16, wave-private region) ----
#pragma unroll
    for (int mt = 0; mt < 2; ++mt)
#pragma unroll
      for (int nt = 0; nt < 8; ++nt)
#pragma unroll
        for (int q = 0; q < 4; ++q)
          P_lds[wave][16 * mt + lg * 4 + q][16 * nt + lr] = __float2bfloat16(s[mt][nt][q]);

    // ---- O += P V (pa: b128 from P; vb: swizzled b128 from Vt tile) ----
    __builtin_amdgcn_s_setprio(1);
#pragma unroll
    for (int ks = 0; ks < 4; ++ks) {
      bf16x8 pa0 = *(const bf16x8*)&P_lds[wave][lr][ks * 32 + lg * 8];
      bf16x8 pa1 = *(const bf16x8*)&P_lds[wave][16 + lr][ks * 32 + lg * 8];
#pragma unroll
      for (int ni = 0; ni < 4; ++ni) {
        const int row = 16 * ni + lr;
        bf16x8 vb = *(const bf16x8*)(sV + row * 256 + ((ks * 64 + lg * 16) ^ ((lr & 7) << 4)));
        oa[0][ni] = MFMA16(pa0, vb, oa[0][ni]);
        oa[1][ni] = MFMA16(pa1, vb, oa[1][ni]);
      }
    }
    __builtin_amdgcn_s_setprio(0);
    __syncthreads();  // P & Vt reads done before next iteration's staging
  }

  // ---- epilogue: O / l ----
#pragma unroll
  for (int mt = 0; mt < 2; ++mt)
#pragma unroll
    for (int ni = 0; ni < 4; ++ni)
#pragma unroll
      for (int q = 0; q < 4; ++q) {
        const int row = qrow0 + 16 * mt + lg * 4 + q;
        const float v = oa[mt][ni][q] / fmaxf(lrun[mt][q], 1e-30f);
        O[base + (size_t)row * 1024 + 16 * ni + lr] = __float2bfloat16(v);
      }
}

extern "C" void kernel_launch(void* const* d_in, const int* in_sizes, int n_in,
                              void* d_out, int out_size, void* d_ws, size_t ws_size,
                              hipStream_t stream) {
  const float* x  = (const float*)d_in[0];
  const float* Wq = (const float*)d_in[1];
  const float* Wk = (const float*)d_in[2];
  const float* Wv = (const float*)d_in[3];
  const float* Wo = (const float*)d_in[4];
  const float* bo = (const float*)d_in[5];
  const void* mask = d_in[6];
  float* out = (float*)d_out;

  __hip_bfloat16* ws = (__hip_bfloat16*)d_ws;
  __hip_bfloat16* xb  = ws;                   // 4096x1024
  __hip_bfloat16* Wqb = ws + 4194304ull;      // 1024x1024
  __hip_bfloat16* Wkb = ws + 5242880ull;
  __hip_bfloat16* Wvb = ws + 6291456ull;
  __hip_bfloat16* Wob = ws + 7340032ull;
  __hip_bfloat16* Qb  = ws + 8388608ull;      // 4096x1024
  __hip_bfloat16* Kb  = ws + 12582912ull;     // 4096x1024
  __hip_bfloat16* Vtb = ws + 16777216ull;     // [2][1024][2048]
  __hip_bfloat16* Ob  = ws + 20971520ull;     // 4096x1024

  dim3 blk(256);
  cvt_kernel<<<2048, blk, 0, stream>>>(x,  (unsigned short*)xb,  524288);
  cvt_kernel<<<512,  blk, 0, stream>>>(Wq, (unsigned short*)Wqb, 131072);
  cvt_kernel<<<512,  blk, 0, stream>>>(Wk, (unsigned short*)Wkb, 131072);
  cvt_kernel<<<512,  blk, 0, stream>>>(Wv, (unsigned short*)Wvb, 131072);
  cvt_kernel<<<512,  blk, 0, stream>>>(Wo, (unsigned short*)Wob, 131072);
  // Q,K projections
  gemm_bt<0><<<dim3(32, 16), blk, 0, stream>>>(xb, Wqb, Wkb, nullptr, Qb, nullptr, 1024);
  // V^T projection
  gemm_bt<2><<<dim3(32, 8), blk, 0, stream>>>(xb, Wvb, nullptr, nullptr, Vtb, nullptr, 1024);
  // block-sparse flash attention
  attn_kernel<<<dim3(16, 32), blk, 0, stream>>>(Qb, Kb, Vtb, mask, Ob);
  // output projection + bias -> f32
  gemm_bt<1><<<dim3(32, 8), blk, 0, stream>>>(Ob, Wob, nullptr, bo, nullptr, out, 1024);
}

// Round 9
// 300.114 us; speedup vs baseline: 1.4427x; 1.1371x over previous
//
#include <hip/hip_runtime.h>
#include <hip/hip_bf16.h>

// B=2, S=2048, D=1024, H=16, DH=64, BLK=128, NB=16
// Inputs FLOAT32 -> bf16 on device. Output FLOAT32.
// V-projection writes V^T (Vt[b][d][s]). Attention: QBLK=64 (grid 1024 blocks,
// 3 blocks/CU by LDS), LDS-staged swizzled K/Vt tiles, 2 barriers/iter.

typedef __attribute__((ext_vector_type(4))) float f32x4;
typedef __attribute__((ext_vector_type(8))) short bf16x8;

#define MFMA16(a, b, c) __builtin_amdgcn_mfma_f32_16x16x32_bf16(a, b, c, 0, 0, 0)
#define LOG2E 1.4426950408889634f

// ---------------- f32 -> bf16 (RNE), 8 elems/thread ----------------
__device__ inline unsigned short f2bf(float f) {
  unsigned u = __builtin_bit_cast(unsigned, f);
  unsigned rounding = 0x7FFFu + ((u >> 16) & 1u);
  return (unsigned short)((u + rounding) >> 16);
}

__global__ __launch_bounds__(256) void cvt_kernel(const float* __restrict__ in,
                                                  unsigned short* __restrict__ out, int n8) {
  const int i = blockIdx.x * 256 + threadIdx.x;
  if (i >= n8) return;
  const float4* p = (const float4*)in + (size_t)i * 2;
  const float4 a = p[0], b = p[1];
  union { unsigned short u[8]; uint4 v; } r;
  r.u[0] = f2bf(a.x); r.u[1] = f2bf(a.y); r.u[2] = f2bf(a.z); r.u[3] = f2bf(a.w);
  r.u[4] = f2bf(b.x); r.u[5] = f2bf(b.y); r.u[6] = f2bf(b.z); r.u[7] = f2bf(b.w);
  *((uint4*)out + i) = r.v;
}

// ---------------- mask dtype sniffer ----------------
__device__ inline int mask_mode(const void* maskp) {
  const unsigned short* mh = (const unsigned short*)maskp;
  const unsigned* mw = (const unsigned*)maskp;
  bool anyFloatHalf = false;
  for (int t = 0; t < 128; ++t) {
    const unsigned short v = mh[t];
    if (v == 0x3F80u || v == 0x3C00u) { anyFloatHalf = true; break; }
  }
  if (anyFloatHalf) {
    bool evenNZ = false;
    for (int t = 0; t < 128; t += 2)
      if (mh[t] != 0) { evenNZ = true; break; }
    return evenNZ ? 1 : 0;  // 1 = bf16/f16, 0 = f32
  }
  bool anyBig = false;
  for (int t = 0; t < 64; ++t)
    if (mw[t] > 1u) { anyBig = true; break; }
  if (anyBig) return 2;  // packed u8
  bool oddNZ = false;
  for (int t = 1; t < 64; t += 2)
    if (mw[t] != 0u) { oddNZ = true; break; }
  return oddNZ ? 3 : 4;  // 3 = i32, 4 = i64
}

__device__ inline int mask_read(const void* maskp, int mode, int idx) {
  switch (mode) {
    case 0: return ((const unsigned*)maskp)[idx] != 0u;
    case 1: return ((const unsigned short*)maskp)[idx] != 0;
    case 2: return ((const unsigned char*)maskp)[idx] != 0;
    case 3: return ((const int*)maskp)[idx] != 0;
    default: return ((const unsigned*)maskp)[idx * 2] != 0u ||
                    ((const unsigned*)maskp)[idx * 2 + 1] != 0u;
  }
}

// ---------------- GEMM staging: 128x32 bf16 tile, linear ----------------
__device__ inline void stage_tile_128x32(const __hip_bfloat16* g, int ld_elems,
                                         __hip_bfloat16* lds, int wave, int lane) {
#pragma unroll
  for (int i = 0; i < 2; ++i) {
    const int chunk = wave * 2 + i;
    const int o = chunk * 1024 + lane * 16;
    const int r = o >> 6;
    const int cb = o & 63;
    const char* ga = (const char*)g + (size_t)r * ld_elems * 2 + cb;
    __builtin_amdgcn_global_load_lds(
        (const __attribute__((address_space(1))) unsigned int*)ga,
        (__attribute__((address_space(3))) unsigned int*)((char*)lds + chunk * 1024),
        16, 0, 0);
  }
}

// ---------------- GEMM: C = A @ W^T.
// MODE 0: fused Q,K (sel=blockIdx.y>>3) -> bf16 [4096][1024] each.
// MODE 1: out proj + f32 bias -> f32 d_out.
// MODE 2: V^T via swapped MFMA operands -> Vt[b][1024][2048] bf16.
template <int MODE>
__global__ __launch_bounds__(256) void gemm_bt(
    const __hip_bfloat16* __restrict__ A,
    const __hip_bfloat16* __restrict__ W0, const __hip_bfloat16* __restrict__ W1,
    const float* __restrict__ bias,
    __hip_bfloat16* __restrict__ OutB, float* __restrict__ OutF, int K) {
  __shared__ __hip_bfloat16 sA[128 * 32];
  __shared__ __hip_bfloat16 sB[128 * 32];
  const int tid = threadIdx.x;
  const int wave = tid >> 6, lane = tid & 63;
  const int lr = lane & 15, lg = lane >> 4;
  const int wr = wave >> 1, wc = wave & 1;
  const int m0 = blockIdx.x * 128;

  const __hip_bfloat16* W;
  __hip_bfloat16* OB = nullptr;
  int n0;
  if (MODE == 0) {
    const int sel = blockIdx.y >> 3;
    n0 = (blockIdx.y & 7) * 128;
    W = sel ? W1 : W0;
    OB = OutB + (size_t)sel * 4194304ull;
  } else {
    n0 = blockIdx.y * 128;
    W = W0;
    OB = OutB;
  }

  f32x4 acc[4][4] = {};
  for (int k0 = 0; k0 < K; k0 += 32) {
    stage_tile_128x32(A + (size_t)m0 * K + k0, K, sA, wave, lane);
    stage_tile_128x32(W + (size_t)n0 * K + k0, K, sB, wave, lane);
    __syncthreads();

    bf16x8 af[4], bfr[4];
#pragma unroll
    for (int mi = 0; mi < 4; ++mi)
      af[mi] = *(const bf16x8*)(sA + (64 * wr + 16 * mi + lr) * 32 + lg * 8);
#pragma unroll
    for (int ni = 0; ni < 4; ++ni)
      bfr[ni] = *(const bf16x8*)(sB + (64 * wc + 16 * ni + lr) * 32 + lg * 8);
#pragma unroll
    for (int i = 0; i < 4; ++i)
#pragma unroll
      for (int jj = 0; jj < 4; ++jj)
        acc[i][jj] = (MODE == 2) ? MFMA16(bfr[i], af[jj], acc[i][jj])   // C^T = W . x^T
                                 : MFMA16(af[i], bfr[jj], acc[i][jj]);
    __syncthreads();
  }

  if (MODE == 2) {
#pragma unroll
    for (int i = 0; i < 4; ++i)
#pragma unroll
      for (int jj = 0; jj < 4; ++jj)
#pragma unroll
        for (int q = 0; q < 4; ++q) {
          const int n = n0 + 64 * wc + 16 * i + lg * 4 + q;
          const int m = m0 + 64 * wr + 16 * jj + lr;
          OB[((size_t)(m >> 11) * 1024 + n) * 2048 + (m & 2047)] =
              __float2bfloat16(acc[i][jj][q]);
        }
  } else {
#pragma unroll
    for (int i = 0; i < 4; ++i)
#pragma unroll
      for (int jj = 0; jj < 4; ++jj)
#pragma unroll
        for (int q = 0; q < 4; ++q) {
          const int m = m0 + 64 * wr + 16 * i + lg * 4 + q;
          const int n = n0 + 64 * wc + 16 * jj + lr;
          if (MODE == 0) OB[(size_t)m * 1024 + n] = __float2bfloat16(acc[i][jj][q]);
          else           OutF[(size_t)m * 1024 + n] = acc[i][jj][q] + bias[n];
        }
  }
}

// ---------------- block-sparse flash attention ----------------
// grid: (32 q-chunks of 64 rows, 32 b*h). 4 waves, wave owns 16 q rows.
// LDS: K 16KB + Vt 16KB + P 17.4KB = 49.4KB -> 3 blocks/CU.
__global__ __launch_bounds__(256) void attn_kernel(
    const __hip_bfloat16* __restrict__ Q, const __hip_bfloat16* __restrict__ K,
    const __hip_bfloat16* __restrict__ Vt, const void* __restrict__ maskp,
    __hip_bfloat16* __restrict__ O) {
  __shared__ char uK[128 * 128];            // K tile [128 s][64 d] swz
  __shared__ char sV[64 * 256];             // Vt tile [64 d][128 s] swz
  __shared__ __hip_bfloat16 P_lds[4][16][136];

  const int qc = blockIdx.x, bh = blockIdx.y;
  const int b = bh >> 4, h = bh & 15;
  const int tid = threadIdx.x, wave = tid >> 6, lane = tid & 63;
  const int lr = lane & 15, lg = lane >> 4;

  const int mmode = mask_mode(maskp);
  const int qb = qc >> 1;                   // mask row (128-row granularity)
  int keep[16], nkeep = 0;
  for (int j = 0; j < 16; ++j)
    if (mask_read(maskp, mmode, qb * 16 + j)) keep[nkeep++] = j;

  const size_t base = (size_t)b * 2048 * 1024 + (size_t)h * 64;          // Q/K/O elem base
  const char* Kbase  = (const char*)(K + base);                          // row stride 2048B
  const char* Vtbase = (const char*)Vt +
      ((size_t)b * 1024 * 2048 + (size_t)h * 64 * 2048) * 2;             // row stride 4096B
  const int qrow0 = qc * 64 + wave * 16;

  bf16x8 qf[2];
#pragma unroll
  for (int ks = 0; ks < 2; ++ks)
    qf[ks] = *(const bf16x8*)(Q + base + (size_t)(qrow0 + lr) * 1024 + ks * 32 + lg * 8);

  f32x4 oa[4] = {};
  float mrun[4], lrun[4];
#pragma unroll
  for (int q = 0; q < 4; ++q) { mrun[q] = -1e30f; lrun[q] = 0.f; }

  for (int ji = 0; ji < nkeep; ++ji) {
    const int j = keep[ji];
    const char* gK = Kbase + (size_t)j * 128 * 2048;   // K rows s=j*128.., 128B used/row
    const char* gV = Vtbase + (size_t)j * 128 * 2;     // Vt cols s=j*128.., 256B used/row

    // ---- stage K and Vt tiles (inverse-swizzled global source, linear LDS dest) ----
#pragma unroll
    for (int i = 0; i < 4; ++i) {
      const int o = (wave * 4 + i) * 1024 + lane * 16;
      { const int r = o >> 7, cb = o & 127, cbs = cb ^ ((r & 7) << 4);
        __builtin_amdgcn_global_load_lds(
            (const __attribute__((address_space(1))) unsigned*)(gK + (size_t)r * 2048 + cbs),
            (__attribute__((address_space(3))) unsigned*)(uK + o), 16, 0, 0); }
      { const int r = o >> 8, cb = o & 255, cbs = cb ^ ((r & 7) << 4);
        __builtin_amdgcn_global_load_lds(
            (const __attribute__((address_space(1))) unsigned*)(gV + (size_t)r * 4096 + cbs),
            (__attribute__((address_space(3))) unsigned*)(sV + o), 16, 0, 0); }
    }
    __syncthreads();  // drain: K/V tiles resident

    // ---- S = Q K^T (kf: swizzled ds_read_b128) ----
    f32x4 s[8] = {};
    __builtin_amdgcn_s_setprio(1);
#pragma unroll
    for (int ks = 0; ks < 2; ++ks)
#pragma unroll
      for (int nt = 0; nt < 8; ++nt) {
        const int row = 16 * nt + lr;
        bf16x8 kf = *(const bf16x8*)(uK + row * 128 + ((ks * 64 + lg * 16) ^ ((lr & 7) << 4)));
        s[nt] = MFMA16(qf[ks], kf, s[nt]);
      }
    __builtin_amdgcn_s_setprio(0);

    // ---- online softmax (rows lg*4+q; 16-lane-group reduce) ----
#pragma unroll
    for (int q = 0; q < 4; ++q) {
      float rm = -1e30f;
#pragma unroll
      for (int nt = 0; nt < 8; ++nt) {
        s[nt][q] *= 0.125f;
        rm = fmaxf(rm, s[nt][q]);
      }
      rm = fmaxf(rm, __shfl_xor(rm, 1));
      rm = fmaxf(rm, __shfl_xor(rm, 2));
      rm = fmaxf(rm, __shfl_xor(rm, 4));
      rm = fmaxf(rm, __shfl_xor(rm, 8));
      const float mold = mrun[q];
      const float mnew = fmaxf(mold, rm);
      const float sf = exp2f((mold - mnew) * LOG2E);
      float rs = 0.f;
#pragma unroll
      for (int nt = 0; nt < 8; ++nt) {
        const float p = exp2f((s[nt][q] - mnew) * LOG2E);
        s[nt][q] = p;
        rs += p;
      }
      rs += __shfl_xor(rs, 1);
      rs += __shfl_xor(rs, 2);
      rs += __shfl_xor(rs, 4);
      rs += __shfl_xor(rs, 8);
      lrun[q] = lrun[q] * sf + rs;
      mrun[q] = mnew;
#pragma unroll
      for (int ni = 0; ni < 4; ++ni) oa[ni][q] *= sf;
    }

    // ---- P -> LDS (bf16, wave-private; same-wave DS ordering) ----
#pragma unroll
    for (int nt = 0; nt < 8; ++nt)
#pragma unroll
      for (int q = 0; q < 4; ++q)
        P_lds[wave][lg * 4 + q][16 * nt + lr] = __float2bfloat16(s[nt][q]);

    // ---- O += P V ----
    __builtin_amdgcn_s_setprio(1);
#pragma unroll
    for (int ks = 0; ks < 4; ++ks) {
      bf16x8 pa = *(const bf16x8*)&P_lds[wave][lr][ks * 32 + lg * 8];
#pragma unroll
      for (int ni = 0; ni < 4; ++ni) {
        const int row = 16 * ni + lr;
        bf16x8 vb = *(const bf16x8*)(sV + row * 256 + ((ks * 64 + lg * 16) ^ ((lr & 7) << 4)));
        oa[ni] = MFMA16(pa, vb, oa[ni]);
      }
    }
    __builtin_amdgcn_s_setprio(0);
    __syncthreads();  // K/V/P reads done before next iteration's staging
  }

  // ---- epilogue: O / l ----
#pragma unroll
  for (int ni = 0; ni < 4; ++ni)
#pragma unroll
    for (int q = 0; q < 4; ++q) {
      const int row = qrow0 + lg * 4 + q;
      const float v = oa[ni][q] / fmaxf(lrun[q], 1e-30f);
      O[base + (size_t)row * 1024 + 16 * ni + lr] = __float2bfloat16(v);
    }
}

extern "C" void kernel_launch(void* const* d_in, const int* in_sizes, int n_in,
                              void* d_out, int out_size, void* d_ws, size_t ws_size,
                              hipStream_t stream) {
  const float* x  = (const float*)d_in[0];
  const float* Wq = (const float*)d_in[1];
  const float* Wk = (const float*)d_in[2];
  const float* Wv = (const float*)d_in[3];
  const float* Wo = (const float*)d_in[4];
  const float* bo = (const float*)d_in[5];
  const void* mask = d_in[6];
  float* out = (float*)d_out;

  __hip_bfloat16* ws = (__hip_bfloat16*)d_ws;
  __hip_bfloat16* xb  = ws;                   // 4096x1024
  __hip_bfloat16* Wqb = ws + 4194304ull;      // 1024x1024
  __hip_bfloat16* Wkb = ws + 5242880ull;
  __hip_bfloat16* Wvb = ws + 6291456ull;
  __hip_bfloat16* Wob = ws + 7340032ull;
  __hip_bfloat16* Qb  = ws + 8388608ull;      // 4096x1024
  __hip_bfloat16* Kb  = ws + 12582912ull;     // 4096x1024
  __hip_bfloat16* Vtb = ws + 16777216ull;     // [2][1024][2048]
  __hip_bfloat16* Ob  = ws + 20971520ull;     // 4096x1024

  dim3 blk(256);
  cvt_kernel<<<2048, blk, 0, stream>>>(x,  (unsigned short*)xb,  524288);
  cvt_kernel<<<512,  blk, 0, stream>>>(Wq, (unsigned short*)Wqb, 131072);
  cvt_kernel<<<512,  blk, 0, stream>>>(Wk, (unsigned short*)Wkb, 131072);
  cvt_kernel<<<512,  blk, 0, stream>>>(Wv, (unsigned short*)Wvb, 131072);
  cvt_kernel<<<512,  blk, 0, stream>>>(Wo, (unsigned short*)Wob, 131072);
  // Q,K projections
  gemm_bt<0><<<dim3(32, 16), blk, 0, stream>>>(xb, Wqb, Wkb, nullptr, Qb, nullptr, 1024);
  // V^T projection
  gemm_bt<2><<<dim3(32, 8), blk, 0, stream>>>(xb, Wvb, nullptr, nullptr, Vtb, nullptr, 1024);
  // block-sparse flash attention (QBLK=64)
  attn_kernel<<<dim3(32, 32), blk, 0, stream>>>(Qb, Kb, Vtb, mask, Ob);
  // output projection + bias -> f32
  gemm_bt<1><<<dim3(32, 8), blk, 0, stream>>>(Ob, Wob, nullptr, bo, nullptr, out, 1024);
}